// Round 18
// baseline (186.061 us; speedup 1.0000x reference)
//
#include <hip/hip_runtime.h>
#include <stdint.h>

#define B_ 2
#define S_ 2048
#define H_ 32
#define KVH_ 8
#define D_ 64
#define HID_ 2048

typedef float f32x4 __attribute__((ext_vector_type(4)));
typedef float f32x16 __attribute__((ext_vector_type(16)));
typedef short bf16x8 __attribute__((ext_vector_type(8)));
typedef unsigned short u16;
typedef unsigned short u16x4 __attribute__((ext_vector_type(4)));
typedef unsigned short u16x8 __attribute__((ext_vector_type(8)));
typedef unsigned int u32;
typedef unsigned int u32x2 __attribute__((ext_vector_type(2)));
typedef unsigned int u32x4 __attribute__((ext_vector_type(4)));

__device__ __forceinline__ u16 f2b(float f) {
  unsigned u = __builtin_bit_cast(unsigned, f);
  u += 0x7fffu + ((u >> 16) & 1u);
  return (u16)(u >> 16);
}
__device__ __forceinline__ float b2f(u16 h) {
  unsigned u = ((unsigned)h) << 16;
  return __builtin_bit_cast(float, u);
}
__device__ __forceinline__ void gl_lds16(const void* g, void* l) {
  __builtin_amdgcn_global_load_lds(
      (const __attribute__((address_space(1))) unsigned*)g,
      (__attribute__((address_space(3))) unsigned*)l, 16, 0, 0);
}
__device__ __forceinline__ f32x4 mfma16(bf16x8 a, bf16x8 b, f32x4 c) {
  return __builtin_amdgcn_mfma_f32_16x16x32_bf16(a, b, c, 0, 0, 0);
}
__device__ __forceinline__ f32x16 mfma32(bf16x8 a, bf16x8 b, f32x16 c) {
  return __builtin_amdgcn_mfma_f32_32x32x16_bf16(a, b, c, 0, 0, 0);
}
__device__ __forceinline__ u32 cvtpk(float lo, float hi) {
  u32 r;
  asm("v_cvt_pk_bf16_f32 %0, %1, %2" : "=v"(r) : "v"(lo), "v"(hi));
  return r;
}
__device__ __forceinline__ float fast_exp2(float x) {
#if __has_builtin(__builtin_amdgcn_exp2f)
  return __builtin_amdgcn_exp2f(x);
#else
  return exp2f(x);
#endif
}
__device__ __forceinline__ void swap32(u32 a, u32 b, u32& x, u32& y) {
#if __has_builtin(__builtin_amdgcn_permlane32_swap)
  auto r = __builtin_amdgcn_permlane32_swap(a, b, false, false);
  x = r[0];
  y = r[1];
#else
  u32 sa = (u32)__shfl_xor((int)a, 32), sb = (u32)__shfl_xor((int)b, 32);
  bool hib = (threadIdx.x & 32) != 0;
  x = hib ? sb : a;
  y = hib ? b : sa;
#endif
}

// ---------------- 1. fused prep: x f32->bf16 cast + all weight transposes ---------
__global__ __launch_bounds__(256) void k_prep(const float* __restrict__ x,
                                              u16* __restrict__ xb,
                                              const float* __restrict__ wq,
                                              const float* __restrict__ wk,
                                              const float* __restrict__ wv,
                                              const float* __restrict__ wo,
                                              u16* __restrict__ wqkvT,
                                              u16* __restrict__ woT) {
  __shared__ float t[32][33];
  int bx = blockIdx.x;
  if (bx < 8192) {
    int i = bx * 256 + threadIdx.x;
    f32x4 v = *(const f32x4*)(x + (size_t)i * 4);
    u16x4 o;
    o[0] = f2b(v[0]); o[1] = f2b(v[1]); o[2] = f2b(v[2]); o[3] = f2b(v[3]);
    *(u16x4*)(xb + (size_t)i * 4) = o;
    return;
  }
  int tt2 = bx - 8192;
  int bxx = tt2 % 160;
  int ky = tt2 / 160;
  const int K = 2048;
  const float* src;
  u16* dst;
  int N, n0;
  if (bxx < 64) {
    src = wq; dst = wqkvT; N = 2048; n0 = bxx * 32;
  } else if (bxx < 80) {
    src = wk; dst = wqkvT + (size_t)2048 * 2048; N = 512; n0 = (bxx - 64) * 32;
  } else if (bxx < 96) {
    src = wv; dst = wqkvT + (size_t)2560 * 2048; N = 512; n0 = (bxx - 80) * 32;
  } else {
    src = wo; dst = woT; N = 2048; n0 = (bxx - 96) * 32;
  }
  int k0 = ky * 32;
  int tt = threadIdx.x;
  int r = tt >> 3, c4 = (tt & 7) << 2;
  f32x4 v = *(const f32x4*)(src + (size_t)(k0 + r) * N + n0 + c4);
  t[r][c4 + 0] = v[0]; t[r][c4 + 1] = v[1];
  t[r][c4 + 2] = v[2]; t[r][c4 + 3] = v[3];
  __syncthreads();
  u16x4 o;
  o[0] = f2b(t[c4 + 0][r]); o[1] = f2b(t[c4 + 1][r]);
  o[2] = f2b(t[c4 + 2][r]); o[3] = f2b(t[c4 + 3][r]);
  *(u16x4*)(dst + (size_t)(n0 + r) * K + k0 + c4) = o;
}

// ---------------- 3. 4-phase 256xBN GEMM, 16 waves (8 staging + 8 compute) --------
__device__ __forceinline__ void stage64(const u16* __restrict__ G, int rowbase,
                                        int K, int kt, u16* unit, int tid) {
  int r = tid >> 3, sl = tid & 7;
  gl_lds16(G + (size_t)(rowbase + r) * K + kt * 64 + ((sl ^ (r & 7)) << 3),
           (char*)unit + tid * 16);
}

template <int BN, int OUTF32>
__global__ __launch_bounds__(1024, 1) void k_gemm8(const u16* __restrict__ A,
                                                   const u16* __restrict__ BT,
                                                   float* __restrict__ Cf,
                                                   u16* __restrict__ Cb,
                                                   int M, int N, int K) {
  constexpr int ATILE = 256 * 64;          // u16 per A tile
  constexpr int BTILE = BN * 64;           // u16 per B tile
  constexpr int BU = BN / 64;              // B 64-row units
  constexpr int WN = 4;                    // waves along N
  constexpr int NI = BN / 64;              // 16-col frags per wave
  constexpr int MI = 4;                    // 16-row frags per wave (64 rows)
  __shared__ __align__(16) u16 sm[2 * ATILE + 2 * BTILE];
  const int tid = threadIdx.x;
  const int l = tid & 63;
  const int lg = (l >> 4) & 3, lr = l & 15;
  const int w = tid >> 6;                  // 0..15
  const int wm = w >> 2, wn = w & 3;
  const bool stager = (w < 8);             // wave-uniform
  const int stid = tid & 511;

  // bijective XCD swizzle (grid % 8 == 0)
  const int nwg = gridDim.x;
  const int cpx = nwg >> 3;
  const int bid = blockIdx.x;
  const int swz = (bid & 7) * cpx + (bid >> 3);
  const int ntn = N / BN;
  const int bm = swz / ntn, bn = swz % ntn;
  const int m0 = bm << 8, n0 = bn * BN;

  const u16* Ag = A + (size_t)m0 * K;
  const u16* Bg = BT + (size_t)n0 * K;
  u16* As = sm;
  u16* Bs = sm + 2 * ATILE;

  const int nt = K >> 6;
  f32x4 acc[MI][NI] = {};

  if (stager) {
#pragma unroll
    for (int u = 0; u < 4; ++u) stage64(Ag, u * 64, K, 0, As + u * 4096, stid);
#pragma unroll
    for (int u = 0; u < BU; ++u) stage64(Bg, u * 64, K, 0, Bs + u * 4096, stid);
    stage64(Ag, 0, K, 1, As + ATILE, stid);
    stage64(Ag, 64, K, 1, As + ATILE + 4096, stid);
    asm volatile("s_waitcnt vmcnt(2)" ::: "memory");
  }
  __builtin_amdgcn_s_barrier();
  asm volatile("" ::: "memory");

  for (int t = 0; t < nt; ++t) {
    const int cur = t & 1;
    u16* Ac = As + cur * ATILE;
    u16* Bc = Bs + cur * BTILE;
    u16* An = As + (cur ^ 1) * ATILE;
    u16* Bn = Bs + (cur ^ 1) * BTILE;
    bf16x8 bc[NI][2];
#pragma unroll
    for (int q = 0; q < 4; ++q) {
      bf16x8 af[2];
#pragma unroll
      for (int ks = 0; ks < 2; ++ks) {
        int row = wm * 64 + q * 16 + lr;
        int slot = (ks * 4 + lg) ^ (lr & 7);
        af[ks] = *(const bf16x8*)&Ac[row * 64 + slot * 8];
      }
      if (q == 0) {
#pragma unroll
        for (int ni = 0; ni < NI; ++ni)
#pragma unroll
          for (int ks = 0; ks < 2; ++ks) {
            int row = wn * (NI * 16) + ni * 16 + lr;
            int slot = (ks * 4 + lg) ^ (lr & 7);
            bc[ni][ks] = *(const bf16x8*)&Bc[row * 64 + slot * 8];
          }
      }
      if (stager && t + 1 < nt) {
        if (q == 0) {
          stage64(Ag, 128, K, t + 1, An + 2 * 4096, stid);
          stage64(Ag, 192, K, t + 1, An + 3 * 4096, stid);
        } else if (q == 1) {
          stage64(Bg, 0, K, t + 1, Bn, stid);
          stage64(Bg, 64, K, t + 1, Bn + 4096, stid);
        } else if (q == 2) {
          if (BU >= 3) stage64(Bg, 128, K, t + 1, Bn + 2 * 4096, stid);
          if (BU >= 4) stage64(Bg, 192, K, t + 1, Bn + 3 * 4096, stid);
        }
      }
      __builtin_amdgcn_s_barrier();
      asm volatile("" ::: "memory");
      __builtin_amdgcn_s_setprio(1);
#pragma unroll
      for (int ni = 0; ni < NI; ++ni)
#pragma unroll
        for (int ks = 0; ks < 2; ++ks)
          acc[q][ni] = mfma16(af[ks], bc[ni][ks], acc[q][ni]);
      __builtin_amdgcn_s_setprio(0);
      if (q == 3) {
        if (stager) {
          if (t + 2 < nt) {
            stage64(Ag, 0, K, t + 2, Ac, stid);
            stage64(Ag, 64, K, t + 2, Ac + 4096, stid);
            asm volatile("s_waitcnt vmcnt(2)" ::: "memory");
          } else if (t + 1 < nt) {
            asm volatile("s_waitcnt vmcnt(0)" ::: "memory");
          }
        }
      }
      __builtin_amdgcn_s_barrier();
      asm volatile("" ::: "memory");
    }
  }

#pragma unroll
  for (int mi = 0; mi < MI; ++mi)
#pragma unroll
    for (int ni = 0; ni < NI; ++ni)
#pragma unroll
      for (int j = 0; j < 4; ++j) {
        size_t row = (size_t)m0 + wm * 64 + mi * 16 + lg * 4 + j;
        size_t col = (size_t)n0 + wn * (NI * 16) + ni * 16 + lr;
        if (OUTF32)
          Cf[row * N + col] = acc[mi][ni][j];
        else
          Cb[row * N + col] = f2b(acc[mi][ni][j]);
      }
}

// ---------------- 4. fused K-RoPE + V-transpose ----------------
__global__ __launch_bounds__(256) void k_ropev(const u16* __restrict__ qkv,
                                               const float* __restrict__ cosb,
                                               const float* __restrict__ sinb,
                                               u16* __restrict__ Kr,
                                               u16* __restrict__ Vt) {
  __shared__ u16 t[64][72];
  int bx = blockIdx.x;
  if (bx < 2048) {
    int task = bx * 16 + (threadIdx.x >> 4);  // (row, kvh)
    int t16 = threadIdx.x & 15;
    int kvh = task & 7;
    int row = task >> 3;
    int b = row >> 11, s = row & (S_ - 1);
    int d2 = t16 * 2;
    const u16* base = qkv + (size_t)row * 3072 + 2048 + kvh * 64;
    u32 lo = *(const u32*)(base + d2);
    u32 hi = *(const u32*)(base + d2 + 32);
    float xl0 = b2f((u16)lo), xl1 = b2f((u16)(lo >> 16));
    float xh0 = b2f((u16)hi), xh1 = b2f((u16)(hi >> 16));
    const float* cb = cosb + s * 64;
    const float* sb = sinb + s * 64;
    float cl0 = cb[d2], cl1 = cb[d2 + 1], ch0 = cb[d2 + 32], ch1 = cb[d2 + 33];
    float sl0 = sb[d2], sl1 = sb[d2 + 1], sh0 = sb[d2 + 32], sh1 = sb[d2 + 33];
    float ol0 = xl0 * cl0 - xh0 * sl0;
    float ol1 = xl1 * cl1 - xh1 * sl1;
    float oh0 = xh0 * ch0 + xl0 * sh0;
    float oh1 = xh1 * ch1 + xl1 * sh1;
    u16* dst = Kr + ((size_t)(b * KVH_ + kvh) * S_ + s) * 64;
    *(u32*)(dst + d2) = (u32)f2b(ol0) | ((u32)f2b(ol1) << 16);
    *(u32*)(dst + d2 + 32) = (u32)f2b(oh0) | ((u32)f2b(oh1) << 16);
    return;
  }
  int bid = bx - 2048;
  int st = bid & 31, kvh = (bid >> 5) & 7, b = bid >> 8;
  int s0 = st * 64;
  int tid = threadIdx.x;
  int sl = tid >> 2, c16 = (tid & 3) << 4;
  const u16* src = qkv + (size_t)(b * S_ + s0 + sl) * 3072 + 2560 + kvh * 64 + c16;
  u16x8 v0 = *(const u16x8*)src;
  u16x8 v1 = *(const u16x8*)(src + 8);
#pragma unroll
  for (int i = 0; i < 8; ++i) { t[sl][c16 + i] = v0[i]; t[sl][c16 + 8 + i] = v1[i]; }
  __syncthreads();
  int dl = tid >> 2, s16 = (tid & 3) << 4;
  u16x8 o0, o1;
#pragma unroll
  for (int i = 0; i < 8; ++i) { o0[i] = t[s16 + i][dl]; o1[i] = t[s16 + 8 + i][dl]; }
  u16* dst = Vt + ((size_t)(b * KVH_ + kvh) * 64 + dl) * S_ + s0 + s16;
  *(u16x8*)dst = o0;
  *(u16x8*)(dst + 8) = o1;
}

// ---------------- 6. Flash attention: paired tiles + split accumulators -----------
// 4 LDS buffers, one barrier+drain per tile-PAIR (R17). NEW: accumulators split
// by tile parity (o*e/l_e even, o*o/l_o odd) so the pair's PV chains are
// independent -> scheduler interleaves QK(t1) || PV(t0) and PV(t1) no longer
// waits on PV(t0). Merged exactly in the epilogue (sum commutes; no-max
// softmax has no cross-tile state).
__device__ __forceinline__ void stage_kv8(const u16* __restrict__ Kg,
                                          const u16* __restrict__ Vg, int k0,
                                          u16* ldsK, u16* ldsV, int tid) {
  int r = tid >> 3, cc = tid & 7;
  gl_lds16(Kg + (size_t)(k0 + r) * 64 + ((cc ^ (r & 7)) << 3), ldsK + tid * 8);
  gl_lds16(Vg + (size_t)r * S_ + k0 + ((cc ^ (r & 7)) << 3), ldsV + tid * 8);
}

__device__ __forceinline__ void repack2(const f32x16 s, bf16x8& f0, bf16x8& f1) {
  bf16x8 outv[2];
#pragma unroll
  for (int h = 0; h < 2; ++h) {
    u32 a0 = cvtpk(s[8 * h + 0], s[8 * h + 1]);
    u32 a1 = cvtpk(s[8 * h + 4], s[8 * h + 5]);
    u32 b0 = cvtpk(s[8 * h + 2], s[8 * h + 3]);
    u32 b1 = cvtpk(s[8 * h + 6], s[8 * h + 7]);
    u32 x0, y0, x1, y1;
    swap32(a0, a1, x0, y0);
    swap32(b0, b1, x1, y1);
    u32x4 t;
    t[0] = x0; t[1] = x1; t[2] = y0; t[3] = y1;
    outv[h] = __builtin_bit_cast(bf16x8, t);
  }
  f0 = outv[0];
  f1 = outv[1];
}

__global__ __launch_bounds__(512) void k_attn(const u16* __restrict__ qkv,
                                              const u16* __restrict__ Kr,
                                              const u16* __restrict__ Vt,
                                              const float* __restrict__ cosb,
                                              const float* __restrict__ sinb,
                                              u16* __restrict__ Oout) {
  __shared__ __align__(16) u16 lds[32768];  // 4 bufs x (K 8KB + V 8KB) = 64 KB
  const int tid = threadIdx.x;
  const int w = tid >> 6, l = tid & 63;
  const int hi = l >> 5, l31 = l & 31;

  const int bid = blockIdx.x;
  const int g = bid >> 6;
  const int qtl = (g < 4) ? (7 - g) : (g - 4);  // pairs (bid,bid+256) sum to 7
  const int hh = (bid >> 1) & 31;
  const int b = bid & 1;
  const int kvh = hh >> 2;
  const int q0 = qtl * 256;
  const int qw0 = q0 + w * 32;
  const int nt = 4 * qtl + 4;  // even, >= 4

  int off8[4];
#pragma unroll
  for (int c = 0; c < 4; ++c)
    off8[c] = l31 * 64 + ((((c << 1) | hi) ^ (l31 & 7)) << 3);

  // ---- fused Q-RoPE: load raw Q, rotate lane-locally, scale by log2(e)/8 ----
  const int s_q = qw0 + l31;
  const u16* qsrc = qkv + (size_t)(b * S_ + s_q) * 3072 + hh * 64;
  bf16x8 qf[4];
  {
    const float* cb = cosb + s_q * 64;
    const float* sb = sinb + s_q * 64;
#pragma unroll
    for (int cp = 0; cp < 2; ++cp) {
      bf16x8 rlo = *(const bf16x8*)(qsrc + cp * 16 + hi * 8);
      bf16x8 rhi = *(const bf16x8*)(qsrc + 32 + cp * 16 + hi * 8);
      int dlo = cp * 16 + hi * 8;
      float ol[8], oh[8];
#pragma unroll
      for (int j = 0; j < 8; ++j) {
        float ql = b2f((u16)rlo[j]), qh = b2f((u16)rhi[j]);
        ol[j] = (ql * cb[dlo + j] - qh * sb[dlo + j]) * 0.18033688f;
        oh[j] = (qh * cb[dlo + 32 + j] + ql * sb[dlo + 32 + j]) * 0.18033688f;
      }
      u32x4 plo, phi;
#pragma unroll
      for (int j2 = 0; j2 < 4; ++j2) {
        plo[j2] = cvtpk(ol[2 * j2], ol[2 * j2 + 1]);
        phi[j2] = cvtpk(oh[2 * j2], oh[2 * j2 + 1]);
      }
      qf[cp] = __builtin_bit_cast(bf16x8, plo);
      qf[cp + 2] = __builtin_bit_cast(bf16x8, phi);
    }
  }

  const u16* Kg = Kr + (size_t)(b * KVH_ + kvh) * S_ * 64;
  const u16* Vg = Vt + (size_t)(b * KVH_ + kvh) * 64 * S_;

  f32x16 o0e = {}, o1e = {}, o0o = {}, o1o = {};
  float l_e = 0.f, l_o = 0.f;

  // one kv-tile into the given accumulator set, from buffer kt%4
  auto TILE = [&](int kt, f32x16& ao0, f32x16& ao1, float& alr) {
    const int k0 = kt * 64;
    if (k0 > qw0 + 31) return;
    const u16* Kc = lds + (kt & 3) * 8192;
    const u16* Vc = Kc + 4096;

    f32x16 sl = {}, sh = {};
    __builtin_amdgcn_s_setprio(1);
#pragma unroll
    for (int c = 0; c < 4; ++c) {
      bf16x8 klo = *(const bf16x8*)(Kc + off8[c]);
      bf16x8 khi = *(const bf16x8*)(Kc + 2048 + off8[c]);
      sl = mfma32(klo, qf[c], sl);
      sh = mfma32(khi, qf[c], sh);
    }
    __builtin_amdgcn_s_setprio(0);

    if (k0 + 63 > qw0) {  // causal mask (diag tiles only)
      int qg = qw0 + l31;
#pragma unroll
      for (int r = 0; r < 16; ++r) {
        int kg = k0 + (r & 3) + 8 * (r >> 2) + 4 * hi;
        if (kg > qg) sl[r] = -3e38f;
        if (kg + 32 > qg) sh[r] = -3e38f;
      }
    }

    // NO-MAX softmax: P = exp2(s) directly (masked -> 0)
    float smv[16];
#pragma unroll
    for (int i = 0; i < 16; ++i) {
      sl[i] = fast_exp2(sl[i]);
      sh[i] = fast_exp2(sh[i]);
      smv[i] = sl[i] + sh[i];
    }
#pragma unroll
    for (int i = 0; i < 8; ++i) smv[i] += smv[i + 8];
#pragma unroll
    for (int i = 0; i < 4; ++i) smv[i] += smv[i + 4];
    smv[0] = (smv[0] + smv[2]) + (smv[1] + smv[3]);
    alr += smv[0] + __shfl_xor(smv[0], 32);

    bf16x8 pf[4];
    repack2(sl, pf[0], pf[1]);
    repack2(sh, pf[2], pf[3]);

    __builtin_amdgcn_s_setprio(1);
#pragma unroll
    for (int sub = 0; sub < 4; ++sub) {
      bf16x8 v0 = *(const bf16x8*)(Vc + off8[sub]);
      bf16x8 v1 = *(const bf16x8*)(Vc + 2048 + off8[sub]);
      ao0 = mfma32(v0, pf[sub], ao0);
      ao1 = mfma32(v1, pf[sub], ao1);
    }
    __builtin_amdgcn_s_setprio(0);
  };

  // prologue: stage tiles 0,1; drain; barrier
  stage_kv8(Kg, Vg, 0, lds, lds + 4096, tid);
  stage_kv8(Kg, Vg, 64, lds + 8192, lds + 12288, tid);
  asm volatile("s_waitcnt vmcnt(0)" ::: "memory");
  __builtin_amdgcn_s_barrier();
  asm volatile("" ::: "memory");

  for (int t0 = 0; t0 < nt; t0 += 2) {
    if (t0 + 2 < nt) {
      u16* nb = lds + ((t0 + 2) & 3) * 8192;
      stage_kv8(Kg, Vg, (t0 + 2) * 64, nb, nb + 4096, tid);
    }
    if (t0 + 3 < nt) {
      u16* nb = lds + ((t0 + 3) & 3) * 8192;
      stage_kv8(Kg, Vg, (t0 + 3) * 64, nb, nb + 4096, tid);
    }
    TILE(t0, o0e, o1e, l_e);
    TILE(t0 + 1, o0o, o1o, l_o);
    asm volatile("s_waitcnt vmcnt(0)" ::: "memory");
    __builtin_amdgcn_s_barrier();
    asm volatile("" ::: "memory");
  }

  // epilogue: merge parity accumulators; O^T -> per-wave LDS -> coalesced stores
  {
    u16* ep = lds + w * 2048;
    float inv = 1.0f / (l_e + l_o);
    float oc[32];
#pragma unroll
    for (int i = 0; i < 16; ++i) {
      oc[i] = o0e[i] + o0o[i];
      oc[16 + i] = o1e[i] + o1o[i];
    }
#pragma unroll
    for (int dh = 0; dh < 2; ++dh)
#pragma unroll
      for (int g2 = 0; g2 < 4; ++g2) {
        u32 w0 = cvtpk(oc[dh * 16 + 4 * g2 + 0] * inv, oc[dh * 16 + 4 * g2 + 1] * inv);
        u32 w1 = cvtpk(oc[dh * 16 + 4 * g2 + 2] * inv, oc[dh * 16 + 4 * g2 + 3] * inv);
        int col = dh * 32 + 8 * g2 + 4 * hi;
        u32x2 tw; tw[0] = w0; tw[1] = w1;
        *(u32x2*)&ep[l31 * 64 + col] = tw;
      }
    asm volatile("s_waitcnt lgkmcnt(0)" ::: "memory");
    int row = l >> 1;
    size_t gb = ((size_t)(b * S_ + q0 + w * 32 + row)) * HID_ + hh * 64 + (l & 1) * 32;
#pragma unroll
    for (int cc = 0; cc < 4; ++cc) {
      u16x8 v = *(const u16x8*)&ep[row * 64 + (l & 1) * 32 + cc * 8];
      *(u16x8*)&Oout[gb + cc * 8] = v;
    }
  }
}

// ---------------- launch ----------------
extern "C" void kernel_launch(void* const* d_in, const int* in_sizes, int n_in,
                              void* d_out, int out_size, void* d_ws, size_t ws_size,
                              hipStream_t stream) {
  (void)in_sizes; (void)n_in; (void)out_size; (void)ws_size;
  const float* x    = (const float*)d_in[0];
  const float* cosb = (const float*)d_in[1];
  const float* sinb = (const float*)d_in[2];
  const float* wq   = (const float*)d_in[3];
  const float* wk   = (const float*)d_in[4];
  const float* wv   = (const float*)d_in[5];
  const float* wo   = (const float*)d_in[6];

  char* wsb = (char*)d_ws;
  u16* xb    = (u16*)(wsb + 0);           // 16,777,216  x bf16 [4096][2048]
  u16* wqkvT = (u16*)(wsb + 16777216);    // 12,582,912  [3072][2048]
  u16* woT   = (u16*)(wsb + 29360128);    //  8,388,608  [2048][2048]
  u16* qkv   = (u16*)(wsb + 37748736);    // 25,165,824  [4096][3072] (Q source for attn)
  u16* attno = (u16*)(wsb + 62914560);    // 16,777,216  [4096][2048] attn out
  u16* Kr    = (u16*)(wsb + 79691776);    //  4,194,304  [2][8][2048][64]
  u16* Vt    = (u16*)(wsb + 83886080);    //  4,194,304  [2][8][64][2048]

  k_prep<<<18432, 256, 0, stream>>>(x, xb, wq, wk, wv, wo, wqkvT, woT);

  k_gemm8<192, 0><<<256, 1024, 0, stream>>>(xb, wqkvT, nullptr, qkv, 4096, 3072, 2048);

  k_ropev<<<2560, 256, 0, stream>>>(qkv, cosb, sinb, Kr, Vt);

  k_attn<<<512, 512, 0, stream>>>(qkv, Kr, Vt, cosb, sinb, attno);

  k_gemm8<128, 1><<<256, 1024, 0, stream>>>(attno, woT, (float*)d_out, nullptr,
                                            4096, 2048, 2048);
}

// Round 19
// 170.084 us; speedup vs baseline: 1.0939x; 1.0939x over previous
//
#include <hip/hip_runtime.h>
#include <stdint.h>

#define B_ 2
#define S_ 2048
#define H_ 32
#define KVH_ 8
#define D_ 64
#define HID_ 2048

typedef float f32x4 __attribute__((ext_vector_type(4)));
typedef float f32x16 __attribute__((ext_vector_type(16)));
typedef short bf16x8 __attribute__((ext_vector_type(8)));
typedef unsigned short u16;
typedef unsigned short u16x4 __attribute__((ext_vector_type(4)));
typedef unsigned short u16x8 __attribute__((ext_vector_type(8)));
typedef unsigned int u32;
typedef unsigned int u32x2 __attribute__((ext_vector_type(2)));
typedef unsigned int u32x4 __attribute__((ext_vector_type(4)));

__device__ __forceinline__ u16 f2b(float f) {
  unsigned u = __builtin_bit_cast(unsigned, f);
  u += 0x7fffu + ((u >> 16) & 1u);
  return (u16)(u >> 16);
}
__device__ __forceinline__ float b2f(u16 h) {
  unsigned u = ((unsigned)h) << 16;
  return __builtin_bit_cast(float, u);
}
__device__ __forceinline__ void gl_lds16(const void* g, void* l) {
  __builtin_amdgcn_global_load_lds(
      (const __attribute__((address_space(1))) unsigned*)g,
      (__attribute__((address_space(3))) unsigned*)l, 16, 0, 0);
}
__device__ __forceinline__ f32x4 mfma16(bf16x8 a, bf16x8 b, f32x4 c) {
  return __builtin_amdgcn_mfma_f32_16x16x32_bf16(a, b, c, 0, 0, 0);
}
__device__ __forceinline__ f32x16 mfma32(bf16x8 a, bf16x8 b, f32x16 c) {
  return __builtin_amdgcn_mfma_f32_32x32x16_bf16(a, b, c, 0, 0, 0);
}
__device__ __forceinline__ u32 cvtpk(float lo, float hi) {
  u32 r;
  asm("v_cvt_pk_bf16_f32 %0, %1, %2" : "=v"(r) : "v"(lo), "v"(hi));
  return r;
}
__device__ __forceinline__ float fast_exp2(float x) {
#if __has_builtin(__builtin_amdgcn_exp2f)
  return __builtin_amdgcn_exp2f(x);
#else
  return exp2f(x);
#endif
}
__device__ __forceinline__ void swap32(u32 a, u32 b, u32& x, u32& y) {
#if __has_builtin(__builtin_amdgcn_permlane32_swap)
  auto r = __builtin_amdgcn_permlane32_swap(a, b, false, false);
  x = r[0];
  y = r[1];
#else
  u32 sa = (u32)__shfl_xor((int)a, 32), sb = (u32)__shfl_xor((int)b, 32);
  bool hib = (threadIdx.x & 32) != 0;
  x = hib ? sb : a;
  y = hib ? b : sa;
#endif
}

// ---------------- 1. fused prep: x f32->bf16 cast + all weight transposes ---------
__global__ __launch_bounds__(256) void k_prep(const float* __restrict__ x,
                                              u16* __restrict__ xb,
                                              const float* __restrict__ wq,
                                              const float* __restrict__ wk,
                                              const float* __restrict__ wv,
                                              const float* __restrict__ wo,
                                              u16* __restrict__ wqkvT,
                                              u16* __restrict__ woT) {
  __shared__ float t[32][33];
  int bx = blockIdx.x;
  if (bx < 8192) {
    int i = bx * 256 + threadIdx.x;
    f32x4 v = *(const f32x4*)(x + (size_t)i * 4);
    u16x4 o;
    o[0] = f2b(v[0]); o[1] = f2b(v[1]); o[2] = f2b(v[2]); o[3] = f2b(v[3]);
    *(u16x4*)(xb + (size_t)i * 4) = o;
    return;
  }
  int tt2 = bx - 8192;
  int bxx = tt2 % 160;
  int ky = tt2 / 160;
  const int K = 2048;
  const float* src;
  u16* dst;
  int N, n0;
  if (bxx < 64) {
    src = wq; dst = wqkvT; N = 2048; n0 = bxx * 32;
  } else if (bxx < 80) {
    src = wk; dst = wqkvT + (size_t)2048 * 2048; N = 512; n0 = (bxx - 64) * 32;
  } else if (bxx < 96) {
    src = wv; dst = wqkvT + (size_t)2560 * 2048; N = 512; n0 = (bxx - 80) * 32;
  } else {
    src = wo; dst = woT; N = 2048; n0 = (bxx - 96) * 32;
  }
  int k0 = ky * 32;
  int tt = threadIdx.x;
  int r = tt >> 3, c4 = (tt & 7) << 2;
  f32x4 v = *(const f32x4*)(src + (size_t)(k0 + r) * N + n0 + c4);
  t[r][c4 + 0] = v[0]; t[r][c4 + 1] = v[1];
  t[r][c4 + 2] = v[2]; t[r][c4 + 3] = v[3];
  __syncthreads();
  u16x4 o;
  o[0] = f2b(t[c4 + 0][r]); o[1] = f2b(t[c4 + 1][r]);
  o[2] = f2b(t[c4 + 2][r]); o[3] = f2b(t[c4 + 3][r]);
  *(u16x4*)(dst + (size_t)(n0 + r) * K + k0 + c4) = o;
}

// ---------------- 3. 4-phase 256xBN GEMM, 16 waves (8 staging + 8 compute) --------
__device__ __forceinline__ void stage64(const u16* __restrict__ G, int rowbase,
                                        int K, int kt, u16* unit, int tid) {
  int r = tid >> 3, sl = tid & 7;
  gl_lds16(G + (size_t)(rowbase + r) * K + kt * 64 + ((sl ^ (r & 7)) << 3),
           (char*)unit + tid * 16);
}

template <int BN, int OUTF32>
__global__ __launch_bounds__(1024, 1) void k_gemm8(const u16* __restrict__ A,
                                                   const u16* __restrict__ BT,
                                                   float* __restrict__ Cf,
                                                   u16* __restrict__ Cb,
                                                   int M, int N, int K) {
  constexpr int ATILE = 256 * 64;          // u16 per A tile
  constexpr int BTILE = BN * 64;           // u16 per B tile
  constexpr int BU = BN / 64;              // B 64-row units
  constexpr int WN = 4;                    // waves along N
  constexpr int NI = BN / 64;              // 16-col frags per wave
  constexpr int MI = 4;                    // 16-row frags per wave (64 rows)
  __shared__ __align__(16) u16 sm[2 * ATILE + 2 * BTILE];
  const int tid = threadIdx.x;
  const int l = tid & 63;
  const int lg = (l >> 4) & 3, lr = l & 15;
  const int w = tid >> 6;                  // 0..15
  const int wm = w >> 2, wn = w & 3;
  const bool stager = (w < 8);             // wave-uniform
  const int stid = tid & 511;

  // bijective XCD swizzle (grid % 8 == 0)
  const int nwg = gridDim.x;
  const int cpx = nwg >> 3;
  const int bid = blockIdx.x;
  const int swz = (bid & 7) * cpx + (bid >> 3);
  const int ntn = N / BN;
  const int bm = swz / ntn, bn = swz % ntn;
  const int m0 = bm << 8, n0 = bn * BN;

  const u16* Ag = A + (size_t)m0 * K;
  const u16* Bg = BT + (size_t)n0 * K;
  u16* As = sm;
  u16* Bs = sm + 2 * ATILE;

  const int nt = K >> 6;
  f32x4 acc[MI][NI] = {};

  if (stager) {
#pragma unroll
    for (int u = 0; u < 4; ++u) stage64(Ag, u * 64, K, 0, As + u * 4096, stid);
#pragma unroll
    for (int u = 0; u < BU; ++u) stage64(Bg, u * 64, K, 0, Bs + u * 4096, stid);
    stage64(Ag, 0, K, 1, As + ATILE, stid);
    stage64(Ag, 64, K, 1, As + ATILE + 4096, stid);
    asm volatile("s_waitcnt vmcnt(2)" ::: "memory");
  }
  __builtin_amdgcn_s_barrier();
  asm volatile("" ::: "memory");

  for (int t = 0; t < nt; ++t) {
    const int cur = t & 1;
    u16* Ac = As + cur * ATILE;
    u16* Bc = Bs + cur * BTILE;
    u16* An = As + (cur ^ 1) * ATILE;
    u16* Bn = Bs + (cur ^ 1) * BTILE;
    bf16x8 bc[NI][2];
#pragma unroll
    for (int q = 0; q < 4; ++q) {
      bf16x8 af[2];
#pragma unroll
      for (int ks = 0; ks < 2; ++ks) {
        int row = wm * 64 + q * 16 + lr;
        int slot = (ks * 4 + lg) ^ (lr & 7);
        af[ks] = *(const bf16x8*)&Ac[row * 64 + slot * 8];
      }
      if (q == 0) {
#pragma unroll
        for (int ni = 0; ni < NI; ++ni)
#pragma unroll
          for (int ks = 0; ks < 2; ++ks) {
            int row = wn * (NI * 16) + ni * 16 + lr;
            int slot = (ks * 4 + lg) ^ (lr & 7);
            bc[ni][ks] = *(const bf16x8*)&Bc[row * 64 + slot * 8];
          }
      }
      if (stager && t + 1 < nt) {
        if (q == 0) {
          stage64(Ag, 128, K, t + 1, An + 2 * 4096, stid);
          stage64(Ag, 192, K, t + 1, An + 3 * 4096, stid);
        } else if (q == 1) {
          stage64(Bg, 0, K, t + 1, Bn, stid);
          stage64(Bg, 64, K, t + 1, Bn + 4096, stid);
        } else if (q == 2) {
          if (BU >= 3) stage64(Bg, 128, K, t + 1, Bn + 2 * 4096, stid);
          if (BU >= 4) stage64(Bg, 192, K, t + 1, Bn + 3 * 4096, stid);
        }
      }
      __builtin_amdgcn_s_barrier();
      asm volatile("" ::: "memory");
      __builtin_amdgcn_s_setprio(1);
#pragma unroll
      for (int ni = 0; ni < NI; ++ni)
#pragma unroll
        for (int ks = 0; ks < 2; ++ks)
          acc[q][ni] = mfma16(af[ks], bc[ni][ks], acc[q][ni]);
      __builtin_amdgcn_s_setprio(0);
      if (q == 3) {
        if (stager) {
          if (t + 2 < nt) {
            stage64(Ag, 0, K, t + 2, Ac, stid);
            stage64(Ag, 64, K, t + 2, Ac + 4096, stid);
            asm volatile("s_waitcnt vmcnt(2)" ::: "memory");
          } else if (t + 1 < nt) {
            asm volatile("s_waitcnt vmcnt(0)" ::: "memory");
          }
        }
      }
      __builtin_amdgcn_s_barrier();
      asm volatile("" ::: "memory");
    }
  }

#pragma unroll
  for (int mi = 0; mi < MI; ++mi)
#pragma unroll
    for (int ni = 0; ni < NI; ++ni)
#pragma unroll
      for (int j = 0; j < 4; ++j) {
        size_t row = (size_t)m0 + wm * 64 + mi * 16 + lg * 4 + j;
        size_t col = (size_t)n0 + wn * (NI * 16) + ni * 16 + lr;
        if (OUTF32)
          Cf[row * N + col] = acc[mi][ni][j];
        else
          Cb[row * N + col] = f2b(acc[mi][ni][j]);
      }
}

// ---------------- 4. fused K-RoPE + V-transpose ----------------
__global__ __launch_bounds__(256) void k_ropev(const u16* __restrict__ qkv,
                                               const float* __restrict__ cosb,
                                               const float* __restrict__ sinb,
                                               u16* __restrict__ Kr,
                                               u16* __restrict__ Vt) {
  __shared__ u16 t[64][72];
  int bx = blockIdx.x;
  if (bx < 2048) {
    int task = bx * 16 + (threadIdx.x >> 4);  // (row, kvh)
    int t16 = threadIdx.x & 15;
    int kvh = task & 7;
    int row = task >> 3;
    int b = row >> 11, s = row & (S_ - 1);
    int d2 = t16 * 2;
    const u16* base = qkv + (size_t)row * 3072 + 2048 + kvh * 64;
    u32 lo = *(const u32*)(base + d2);
    u32 hi = *(const u32*)(base + d2 + 32);
    float xl0 = b2f((u16)lo), xl1 = b2f((u16)(lo >> 16));
    float xh0 = b2f((u16)hi), xh1 = b2f((u16)(hi >> 16));
    const float* cb = cosb + s * 64;
    const float* sb = sinb + s * 64;
    float cl0 = cb[d2], cl1 = cb[d2 + 1], ch0 = cb[d2 + 32], ch1 = cb[d2 + 33];
    float sl0 = sb[d2], sl1 = sb[d2 + 1], sh0 = sb[d2 + 32], sh1 = sb[d2 + 33];
    float ol0 = xl0 * cl0 - xh0 * sl0;
    float ol1 = xl1 * cl1 - xh1 * sl1;
    float oh0 = xh0 * ch0 + xl0 * sh0;
    float oh1 = xh1 * ch1 + xl1 * sh1;
    u16* dst = Kr + ((size_t)(b * KVH_ + kvh) * S_ + s) * 64;
    *(u32*)(dst + d2) = (u32)f2b(ol0) | ((u32)f2b(ol1) << 16);
    *(u32*)(dst + d2 + 32) = (u32)f2b(oh0) | ((u32)f2b(oh1) << 16);
    return;
  }
  int bid = bx - 2048;
  int st = bid & 31, kvh = (bid >> 5) & 7, b = bid >> 8;
  int s0 = st * 64;
  int tid = threadIdx.x;
  int sl = tid >> 2, c16 = (tid & 3) << 4;
  const u16* src = qkv + (size_t)(b * S_ + s0 + sl) * 3072 + 2560 + kvh * 64 + c16;
  u16x8 v0 = *(const u16x8*)src;
  u16x8 v1 = *(const u16x8*)(src + 8);
#pragma unroll
  for (int i = 0; i < 8; ++i) { t[sl][c16 + i] = v0[i]; t[sl][c16 + 8 + i] = v1[i]; }
  __syncthreads();
  int dl = tid >> 2, s16 = (tid & 3) << 4;
  u16x8 o0, o1;
#pragma unroll
  for (int i = 0; i < 8; ++i) { o0[i] = t[s16 + i][dl]; o1[i] = t[s16 + 8 + i][dl]; }
  u16* dst = Vt + ((size_t)(b * KVH_ + kvh) * 64 + dl) * S_ + s0 + s16;
  *(u16x8*)dst = o0;
  *(u16x8*)(dst + 8) = o1;
}

// ---------------- 6. Flash attention: 8-wave QBLK=256, paired-tile barriers -------
// 4 LDS buffers (64 KB); ONE barrier + ONE vmcnt(0) per tile-PAIR. Pair p:
// stage tiles 2p+2, 2p+3 (their buffers were last read in pair p-1, protected
// by p-1's end barrier), compute tiles 2p, 2p+1 in a barrier-free region,
// drain+barrier. Single accumulator set (R18's split-acc regressed: +VGPR ->
// occupancy cliff). nt = 4*qtl+4 is always even.
__device__ __forceinline__ void stage_kv8(const u16* __restrict__ Kg,
                                          const u16* __restrict__ Vg, int k0,
                                          u16* ldsK, u16* ldsV, int tid) {
  int r = tid >> 3, cc = tid & 7;
  gl_lds16(Kg + (size_t)(k0 + r) * 64 + ((cc ^ (r & 7)) << 3), ldsK + tid * 8);
  gl_lds16(Vg + (size_t)r * S_ + k0 + ((cc ^ (r & 7)) << 3), ldsV + tid * 8);
}

__device__ __forceinline__ void repack2(const f32x16 s, bf16x8& f0, bf16x8& f1) {
  bf16x8 outv[2];
#pragma unroll
  for (int h = 0; h < 2; ++h) {
    u32 a0 = cvtpk(s[8 * h + 0], s[8 * h + 1]);
    u32 a1 = cvtpk(s[8 * h + 4], s[8 * h + 5]);
    u32 b0 = cvtpk(s[8 * h + 2], s[8 * h + 3]);
    u32 b1 = cvtpk(s[8 * h + 6], s[8 * h + 7]);
    u32 x0, y0, x1, y1;
    swap32(a0, a1, x0, y0);
    swap32(b0, b1, x1, y1);
    u32x4 t;
    t[0] = x0; t[1] = x1; t[2] = y0; t[3] = y1;
    outv[h] = __builtin_bit_cast(bf16x8, t);
  }
  f0 = outv[0];
  f1 = outv[1];
}

__global__ __launch_bounds__(512) void k_attn(const u16* __restrict__ qkv,
                                              const u16* __restrict__ Kr,
                                              const u16* __restrict__ Vt,
                                              const float* __restrict__ cosb,
                                              const float* __restrict__ sinb,
                                              u16* __restrict__ Oout) {
  __shared__ __align__(16) u16 lds[32768];  // 4 bufs x (K 8KB + V 8KB) = 64 KB
  const int tid = threadIdx.x;
  const int w = tid >> 6, l = tid & 63;
  const int hi = l >> 5, l31 = l & 31;

  const int bid = blockIdx.x;
  const int g = bid >> 6;
  const int qtl = (g < 4) ? (7 - g) : (g - 4);  // pairs (bid,bid+256) sum to 7
  const int hh = (bid >> 1) & 31;
  const int b = bid & 1;
  const int kvh = hh >> 2;
  const int q0 = qtl * 256;
  const int qw0 = q0 + w * 32;
  const int nt = 4 * qtl + 4;  // even, >= 4

  int off8[4];
#pragma unroll
  for (int c = 0; c < 4; ++c)
    off8[c] = l31 * 64 + ((((c << 1) | hi) ^ (l31 & 7)) << 3);

  // ---- fused Q-RoPE: load raw Q, rotate lane-locally, scale by log2(e)/8 ----
  const int s_q = qw0 + l31;
  const u16* qsrc = qkv + (size_t)(b * S_ + s_q) * 3072 + hh * 64;
  bf16x8 qf[4];
  {
    const float* cb = cosb + s_q * 64;
    const float* sb = sinb + s_q * 64;
#pragma unroll
    for (int cp = 0; cp < 2; ++cp) {
      bf16x8 rlo = *(const bf16x8*)(qsrc + cp * 16 + hi * 8);
      bf16x8 rhi = *(const bf16x8*)(qsrc + 32 + cp * 16 + hi * 8);
      int dlo = cp * 16 + hi * 8;
      float ol[8], oh[8];
#pragma unroll
      for (int j = 0; j < 8; ++j) {
        float ql = b2f((u16)rlo[j]), qh = b2f((u16)rhi[j]);
        ol[j] = (ql * cb[dlo + j] - qh * sb[dlo + j]) * 0.18033688f;
        oh[j] = (qh * cb[dlo + 32 + j] + ql * sb[dlo + 32 + j]) * 0.18033688f;
      }
      u32x4 plo, phi;
#pragma unroll
      for (int j2 = 0; j2 < 4; ++j2) {
        plo[j2] = cvtpk(ol[2 * j2], ol[2 * j2 + 1]);
        phi[j2] = cvtpk(oh[2 * j2], oh[2 * j2 + 1]);
      }
      qf[cp] = __builtin_bit_cast(bf16x8, plo);
      qf[cp + 2] = __builtin_bit_cast(bf16x8, phi);
    }
  }

  const u16* Kg = Kr + (size_t)(b * KVH_ + kvh) * S_ * 64;
  const u16* Vg = Vt + (size_t)(b * KVH_ + kvh) * 64 * S_;

  f32x16 o0 = {}, o1 = {};
  float l_run = 0.f;

  // one kv-tile: QK -> mask -> exp2 -> sum -> repack -> PV, from buffer kt%4
  auto TILE = [&](int kt) {
    const int k0 = kt * 64;
    if (k0 > qw0 + 31) return;
    const u16* Kc = lds + (kt & 3) * 8192;
    const u16* Vc = Kc + 4096;

    f32x16 sl = {}, sh = {};
    __builtin_amdgcn_s_setprio(1);
#pragma unroll
    for (int c = 0; c < 4; ++c) {
      bf16x8 klo = *(const bf16x8*)(Kc + off8[c]);
      bf16x8 khi = *(const bf16x8*)(Kc + 2048 + off8[c]);
      sl = mfma32(klo, qf[c], sl);
      sh = mfma32(khi, qf[c], sh);
    }
    __builtin_amdgcn_s_setprio(0);

    if (k0 + 63 > qw0) {  // causal mask (diag tiles only)
      int qg = qw0 + l31;
#pragma unroll
      for (int r = 0; r < 16; ++r) {
        int kg = k0 + (r & 3) + 8 * (r >> 2) + 4 * hi;
        if (kg > qg) sl[r] = -3e38f;
        if (kg + 32 > qg) sh[r] = -3e38f;
      }
    }

    // NO-MAX softmax: P = exp2(s) directly (masked -> 0)
    float smv[16];
#pragma unroll
    for (int i = 0; i < 16; ++i) {
      sl[i] = fast_exp2(sl[i]);
      sh[i] = fast_exp2(sh[i]);
      smv[i] = sl[i] + sh[i];
    }
#pragma unroll
    for (int i = 0; i < 8; ++i) smv[i] += smv[i + 8];
#pragma unroll
    for (int i = 0; i < 4; ++i) smv[i] += smv[i + 4];
    smv[0] = (smv[0] + smv[2]) + (smv[1] + smv[3]);
    l_run += smv[0] + __shfl_xor(smv[0], 32);

    bf16x8 pf[4];
    repack2(sl, pf[0], pf[1]);
    repack2(sh, pf[2], pf[3]);

    __builtin_amdgcn_s_setprio(1);
#pragma unroll
    for (int sub = 0; sub < 4; ++sub) {
      bf16x8 v0 = *(const bf16x8*)(Vc + off8[sub]);
      bf16x8 v1 = *(const bf16x8*)(Vc + 2048 + off8[sub]);
      o0 = mfma32(v0, pf[sub], o0);
      o1 = mfma32(v1, pf[sub], o1);
    }
    __builtin_amdgcn_s_setprio(0);
  };

  // prologue: stage tiles 0,1; drain; barrier
  stage_kv8(Kg, Vg, 0, lds, lds + 4096, tid);
  stage_kv8(Kg, Vg, 64, lds + 8192, lds + 12288, tid);
  asm volatile("s_waitcnt vmcnt(0)" ::: "memory");
  __builtin_amdgcn_s_barrier();
  asm volatile("" ::: "memory");

  for (int t0 = 0; t0 < nt; t0 += 2) {
    if (t0 + 2 < nt) {
      u16* nb = lds + ((t0 + 2) & 3) * 8192;
      stage_kv8(Kg, Vg, (t0 + 2) * 64, nb, nb + 4096, tid);
    }
    if (t0 + 3 < nt) {
      u16* nb = lds + ((t0 + 3) & 3) * 8192;
      stage_kv8(Kg, Vg, (t0 + 3) * 64, nb, nb + 4096, tid);
    }
    TILE(t0);
    TILE(t0 + 1);
    asm volatile("s_waitcnt vmcnt(0)" ::: "memory");
    __builtin_amdgcn_s_barrier();
    asm volatile("" ::: "memory");
  }

  // epilogue: O^T -> per-wave LDS [32 q][64 d] -> coalesced 16B stores
  {
    u16* ep = lds + w * 2048;
    float inv = 1.0f / l_run;
    float oc[32];
#pragma unroll
    for (int i = 0; i < 16; ++i) { oc[i] = o0[i]; oc[16 + i] = o1[i]; }
#pragma unroll
    for (int dh = 0; dh < 2; ++dh)
#pragma unroll
      for (int g2 = 0; g2 < 4; ++g2) {
        u32 w0 = cvtpk(oc[dh * 16 + 4 * g2 + 0] * inv, oc[dh * 16 + 4 * g2 + 1] * inv);
        u32 w1 = cvtpk(oc[dh * 16 + 4 * g2 + 2] * inv, oc[dh * 16 + 4 * g2 + 3] * inv);
        int col = dh * 32 + 8 * g2 + 4 * hi;
        u32x2 tw; tw[0] = w0; tw[1] = w1;
        *(u32x2*)&ep[l31 * 64 + col] = tw;
      }
    asm volatile("s_waitcnt lgkmcnt(0)" ::: "memory");
    int row = l >> 1;
    size_t gb = ((size_t)(b * S_ + q0 + w * 32 + row)) * HID_ + hh * 64 + (l & 1) * 32;
#pragma unroll
    for (int cc = 0; cc < 4; ++cc) {
      u16x8 v = *(const u16x8*)&ep[row * 64 + (l & 1) * 32 + cc * 8];
      *(u16x8*)&Oout[gb + cc * 8] = v;
    }
  }
}

// ---------------- launch ----------------
extern "C" void kernel_launch(void* const* d_in, const int* in_sizes, int n_in,
                              void* d_out, int out_size, void* d_ws, size_t ws_size,
                              hipStream_t stream) {
  (void)in_sizes; (void)n_in; (void)out_size; (void)ws_size;
  const float* x    = (const float*)d_in[0];
  const float* cosb = (const float*)d_in[1];
  const float* sinb = (const float*)d_in[2];
  const float* wq   = (const float*)d_in[3];
  const float* wk   = (const float*)d_in[4];
  const float* wv   = (const float*)d_in[5];
  const float* wo   = (const float*)d_in[6];

  char* wsb = (char*)d_ws;
  u16* xb    = (u16*)(wsb + 0);           // 16,777,216  x bf16 [4096][2048]
  u16* wqkvT = (u16*)(wsb + 16777216);    // 12,582,912  [3072][2048]
  u16* woT   = (u16*)(wsb + 29360128);    //  8,388,608  [2048][2048]
  u16* qkv   = (u16*)(wsb + 37748736);    // 25,165,824  [4096][3072] (Q source for attn)
  u16* attno = (u16*)(wsb + 62914560);    // 16,777,216  [4096][2048] attn out
  u16* Kr    = (u16*)(wsb + 79691776);    //  4,194,304  [2][8][2048][64]
  u16* Vt    = (u16*)(wsb + 83886080);    //  4,194,304  [2][8][64][2048]

  k_prep<<<18432, 256, 0, stream>>>(x, xb, wq, wk, wv, wo, wqkvT, woT);

  k_gemm8<192, 0><<<256, 1024, 0, stream>>>(xb, wqkvT, nullptr, qkv, 4096, 3072, 2048);

  k_ropev<<<2560, 256, 0, stream>>>(qkv, cosb, sinb, Kr, Vt);

  k_attn<<<512, 512, 0, stream>>>(qkv, Kr, Vt, cosb, sinb, attno);

  k_gemm8<128, 1><<<256, 1024, 0, stream>>>(attno, woT, (float*)d_out, nullptr,
                                            4096, 2048, 2048);
}